// Round 4
// baseline (149.900 us; speedup 1.0000x reference)
//
#include <hip/hip_runtime.h>

#define NQ      10
#define NLAYERS 4
#define D_IN    784
#define BLOCK   256            // 4 waves per workgroup, TWO states per wave (pk-packed).
// R16: waves_per_eu(4,8) -> (2,8). R15's state-packed layout needs ~110-130 live regs;
// (4,8) caps the budget at 512/4=128 total and the allocator spilled ~50 regs to scratch
// (WRITE_SIZE 6.4MB, VALUBusy fell 76->55% on scratch vmcnt stalls). (2,8) gives a 256-reg
// budget: statevector + G2 coefficients stay in registers. Grid supplies 16 waves/CU;
// ~128-reg use still allows 4 waves/SIMD, so residency should be flat and only the
// scratch round-trips disappear.
// Register-file model (m69): per-SIMD file = 512 regs (waves halve at 64/128/256).
// Tripwire: WRITE_SIZE must return to ~0.3 MB. If it stays MBs, allocator still short ->
// next step is SGPR gate table via d_ws precompute kernel.
// LOCKED: reductions use plain __shfl_xor only (R8 DPP reductions diverged across graph
// replays). DPP stays confined to lane_xor<1,2> under full exec (stable since R4).

// Amplitude index i (10 bits): i = lane(6 bits, i[9:4]) * 16 + r(4 bits, i[3:0]).
// Qubit q sits at bit P = 9-q.  P>=4 -> lane qubit (lane bit P-4), P<4 -> register qubit.

typedef __attribute__((ext_vector_type(2))) float f2;

__device__ __forceinline__ f2 sp(float v) { f2 r; r.x = v; r.y = v; return r; }

struct G2 { f2 Ax, Ay, Az, Aw, Bx, By, Bz, Bw; };   // u00=(Ax,Ay) u01=(Az,Aw) u10=(Bx,By) u11=(Bz,Bw)

template<int LB>
__device__ __forceinline__ float lane_xor(float v) {
    if constexpr (LB == 1) {        // quad_perm [1,0,3,2]
        return __int_as_float(__builtin_amdgcn_update_dpp(
            0, __float_as_int(v), 0xB1, 0xF, 0xF, false));
    } else if constexpr (LB == 2) { // quad_perm [2,3,0,1]
        return __int_as_float(__builtin_amdgcn_update_dpp(
            0, __float_as_int(v), 0x4E, 0xF, 0xF, false));
    } else {
        return __shfl_xor(v, LB, 64);
    }
}

template<int LB>
__device__ __forceinline__ f2 lane_xor2(f2 v) {
    f2 r; r.x = lane_xor<LB>(v.x); r.y = lane_xor<LB>(v.y); return r;
}

// ---- permlane pair swap (VALU pipe): exchanges lane-halves between two registers ----
template<int HALF>   // HALF = 32 (v_permlane32_swap) or 16 (v_permlane16_swap)
__device__ __forceinline__ void plswap(f2 &d, f2 &s) {
    if constexpr (HALF == 32) {
        auto rx = __builtin_amdgcn_permlane32_swap(__float_as_int(d.x), __float_as_int(s.x), false, false);
        auto ry = __builtin_amdgcn_permlane32_swap(__float_as_int(d.y), __float_as_int(s.y), false, false);
        d.x = __int_as_float(rx[0]); s.x = __int_as_float(rx[1]);
        d.y = __int_as_float(ry[0]); s.y = __int_as_float(ry[1]);
    } else {
        auto rx = __builtin_amdgcn_permlane16_swap(__float_as_int(d.x), __float_as_int(s.x), false, false);
        auto ry = __builtin_amdgcn_permlane16_swap(__float_as_int(d.y), __float_as_int(s.y), false, false);
        d.x = __int_as_float(rx[0]); s.x = __int_as_float(rx[1]);
        d.y = __int_as_float(ry[0]); s.y = __int_as_float(ry[1]);
    }
}

// ---- Rot on lane bit HALF via permlane pair-processing (coefs uniform across lanes) ----
template<int HALF>
__device__ __forceinline__ void rot_gate_pl_c(f2 (&re)[16], f2 (&im)[16], const G2& g) {
#pragma unroll
    for (int r = 0; r < 16; r += 2) {
        f2 ur = re[r], vr = re[r + 1], ui = im[r], vi = im[r + 1];
        plswap<HALF>(ur, vr); plswap<HALF>(ui, vi);
        // (ur,ui) = bit=0 amp, (vr,vi) = bit=1 amp, in every lane
        f2 nur = g.Ax*ur - g.Ay*ui + g.Az*vr - g.Aw*vi;
        f2 nui = g.Ax*ui + g.Ay*ur + g.Az*vi + g.Aw*vr;
        f2 nvr = g.Bx*ur - g.By*ui + g.Bz*vr - g.Bw*vi;
        f2 nvi = g.Bx*ui + g.By*ur + g.Bz*vi + g.Bw*vr;
        plswap<HALF>(nur, nvr); plswap<HALF>(nui, nvi);
        re[r] = nur; re[r + 1] = nvr; im[r] = nui; im[r + 1] = nvi;
    }
}

// ---- rot<9> with PREVIOUS layer's CNOT(ctrl=reg bit0, tgt=lane bit32) fused in ----
__device__ __forceinline__ void rot9_fused_c(f2 (&re)[16], f2 (&im)[16], int lane, const G2& g) {
    const bool hi = (lane & 32) != 0;
    // lanes<32 process even r (normal roles); lanes>=32 process odd r (CNOT-swapped roles)
    const f2 cAx = hi ? g.Az : g.Ax, cAy = hi ? g.Aw : g.Ay;   // coef on u
    const f2 cAz = hi ? g.Ax : g.Az, cAw = hi ? g.Ay : g.Aw;   // coef on v
    const f2 cBx = hi ? g.Bz : g.Bx, cBy = hi ? g.Bw : g.By;
    const f2 cBz = hi ? g.Bx : g.Bz, cBw = hi ? g.By : g.Bw;
#pragma unroll
    for (int r = 0; r < 16; r += 2) {
        f2 ur = re[r], vr = re[r + 1], ui = im[r], vi = im[r + 1];
        plswap<32>(ur, vr); plswap<32>(ui, vi);
        f2 nur = cAx*ur - cAy*ui + cAz*vr - cAw*vi;
        f2 nui = cAx*ui + cAy*ur + cAz*vi + cAw*vr;
        f2 nvr = cBx*ur - cBy*ui + cBz*vr - cBw*vi;
        f2 nvi = cBx*ui + cBy*ur + cBz*vi + cBw*vr;
        plswap<32>(nur, nvr); plswap<32>(nui, nvi);
        re[r] = nur; re[r + 1] = nvr; im[r] = nui; im[r + 1] = nvi;
    }
}

// ---- generic Rot on bit P (P=7..4 lane via DS/DPP, P<4 register pairs) ----
template<int P>
__device__ __forceinline__ void rot_gate_c(f2 (&re)[16], f2 (&im)[16], int lane, const G2& g) {
    if constexpr (P >= 4) {
        const int lb = 1 << (P - 4);
        const bool hi = (lane & lb) != 0;
        const f2 gdx = hi ? g.Bz : g.Ax, gdy = hi ? g.Bw : g.Ay;   // diagonal coef
        const f2 gox = hi ? g.Bx : g.Az, goy = hi ? g.By : g.Aw;   // off-diagonal coef
#pragma unroll
        for (int r = 0; r < 16; r++) {
            f2 ore = lane_xor2<lb>(re[r]);
            f2 oim = lane_xor2<lb>(im[r]);
            f2 vr = re[r], vi = im[r];
            re[r] = gdx*vr - gdy*vi + gox*ore - goy*oim;
            im[r] = gdx*vi + gdy*vr + gox*oim + goy*ore;
        }
    } else {
        const int m = 1 << P;
#pragma unroll
        for (int r = 0; r < 16; r++) {
            if (!(r & m)) {
                const int r1 = r | m;
                f2 r0r = re[r], r0i = im[r], r1r = re[r1], r1i = im[r1];
                re[r]  = g.Ax*r0r - g.Ay*r0i + g.Az*r1r - g.Aw*r1i;
                im[r]  = g.Ax*r0i + g.Ay*r0r + g.Az*r1i + g.Aw*r1r;
                re[r1] = g.Bx*r0r - g.By*r0i + g.Bz*r1r - g.Bw*r1i;
                im[r1] = g.Bx*r0i + g.By*r0r + g.Bz*r1i + g.Bw*r1r;
            }
        }
    }
}

// ---- CNOT: control bit PC, target bit PT ----
template<int PC, int PT>
__device__ __forceinline__ void cnot_gate_c(f2 (&re)[16], f2 (&im)[16], int lane) {
    if constexpr (PC >= 4 && PT < 4) {                // lane control, register target
        const int mt = 1 << PT;
        const bool ctl = (lane & (1 << (PC - 4))) != 0;
#pragma unroll
        for (int r = 0; r < 16; r++) {
            if (!(r & mt)) {
                const int r1 = r | mt;
                f2 A0 = re[r], A1 = re[r1], B0 = im[r], B1 = im[r1];
                f2 n0, n1, m0, m1;
                n0.x = ctl ? A1.x : A0.x;  n0.y = ctl ? A1.y : A0.y;
                n1.x = ctl ? A0.x : A1.x;  n1.y = ctl ? A0.y : A1.y;
                m0.x = ctl ? B1.x : B0.x;  m0.y = ctl ? B1.y : B0.y;
                m1.x = ctl ? B0.x : B1.x;  m1.y = ctl ? B0.y : B1.y;
                re[r] = n0; re[r1] = n1; im[r] = m0; im[r1] = m1;
            }
        }
    } else if constexpr (PC < 4 && PT >= 4) {         // register control, lane target
        const int mc = 1 << PC, mt = 1 << (PT - 4);
#pragma unroll
        for (int r = 0; r < 16; r++) {
            if (r & mc) {
                re[r].x = __shfl_xor(re[r].x, mt, 64);
                re[r].y = __shfl_xor(re[r].y, mt, 64);
                im[r].x = __shfl_xor(im[r].x, mt, 64);
                im[r].y = __shfl_xor(im[r].y, mt, 64);
            }
        }
    } else {                                          // register-register: free rename
        const int mc = 1 << PC, mt = 1 << PT;
#pragma unroll
        for (int r = 0; r < 16; r++) {
            if ((r & mc) && !(r & mt)) {
                const int r1 = r | mt;
                f2 t = re[r]; re[r] = re[r1]; re[r1] = t;
                f2 u = im[r]; im[r] = im[r1]; im[r1] = u;
            }
        }
    }
}

__device__ __forceinline__ G2 load_g(const float* gl, int q) {
    float4 gA = *(const float4*)(gl + q * 8);
    float4 gB = *(const float4*)(gl + q * 8 + 4);
    G2 g;
    g.Ax = sp(gA.x); g.Ay = sp(gA.y); g.Az = sp(gA.z); g.Aw = sp(gA.w);
    g.Bx = sp(gB.x); g.By = sp(gB.y); g.Bz = sp(gB.z); g.Bw = sp(gB.w);
    return g;
}

__global__ __launch_bounds__(BLOCK)
__attribute__((amdgpu_waves_per_eu(2, 8)))
void qnet_kernel(
    const float* __restrict__ x,
    const float* __restrict__ Wp,
    const float* __restrict__ bp,
    const float* __restrict__ qw,
    const float* __restrict__ Wo,
    const float* __restrict__ bo,
    float* __restrict__ out, int B)
{
    __shared__ __align__(16) float gates[NLAYERS * NQ * 8];  // per-WG Rot matrix table

    const int tid  = threadIdx.x;
    const int lane = tid & 63;
    const int s0   = (blockIdx.x * (BLOCK / 64) + (tid >> 6)) * 2;  // two states per wave
    const int s1   = s0 + 1;

    // ---- Rot gate table (built once per workgroup, shared by 4 waves / 8 states) ----
    if (tid < NLAYERS * NQ) {
        float phi = qw[tid * 3 + 0];
        float th  = qw[tid * 3 + 1];
        float om  = qw[tid * 3 + 2];
        float sth, cth; sincosf(0.5f * th, &sth, &cth);
        float sap, cap; sincosf(0.5f * (phi + om), &sap, &cap);
        float sam, cam; sincosf(0.5f * (phi - om), &sam, &cam);
        float* g = &gates[tid * 8];
        g[0] =  cap * cth;  g[1] = -sap * cth;   // u00
        g[2] = -cam * sth;  g[3] = -sam * sth;   // u01
        g[4] =  cam * sth;  g[5] = -sam * sth;   // u10
        g[6] =  cap * cth;  g[7] =  sap * cth;   // u11
    }
    __syncthreads();
    if (s0 >= B) return;

    // ---- projection for both states (Wp load shared; float4: 784 = 3*256 + 16) ----
    float acc0[NQ], acc1[NQ];
#pragma unroll
    for (int q = 0; q < NQ; q++) { acc0[q] = 0.f; acc1[q] = 0.f; }
    const float* xr0 = x + (size_t)s0 * D_IN;
    const float* xr1 = x + (size_t)s1 * D_IN;
#pragma unroll
    for (int it = 0; it < 3; it++) {
        const int d = (it * 64 + lane) * 4;
        float4 xv0 = *(const float4*)(xr0 + d);
        float4 xv1 = *(const float4*)(xr1 + d);
#pragma unroll
        for (int q = 0; q < NQ; q++) {
            float4 wv = *(const float4*)(Wp + q * D_IN + d);
            acc0[q] += xv0.x * wv.x + xv0.y * wv.y + xv0.z * wv.z + xv0.w * wv.w;
            acc1[q] += xv1.x * wv.x + xv1.y * wv.y + xv1.z * wv.z + xv1.w * wv.w;
        }
    }
    if (lane < 4) {                                    // tail 768..783
        const int d = (192 + lane) * 4;
        float4 xv0 = *(const float4*)(xr0 + d);
        float4 xv1 = *(const float4*)(xr1 + d);
#pragma unroll
        for (int q = 0; q < NQ; q++) {
            float4 wv = *(const float4*)(Wp + q * D_IN + d);
            acc0[q] += xv0.x * wv.x + xv0.y * wv.y + xv0.z * wv.z + xv0.w * wv.w;
            acc1[q] += xv1.x * wv.x + xv1.y * wv.y + xv1.z * wv.z + xv1.w * wv.w;
        }
    }
#pragma unroll
    for (int q = 0; q < NQ; q++) {
#pragma unroll
        for (int o = 1; o < 64; o <<= 1) {
            acc0[q] += __shfl_xor(acc0[q], o, 64);
            acc1[q] += __shfl_xor(acc1[q], o, 64);
        }
    }
    float myc0 = 1.f, mys0 = 0.f, myc1 = 1.f, mys1 = 0.f;
    if (lane < NQ) {
        float h0 = tanhf(acc0[lane] + bp[lane]);
        float h1 = tanhf(acc1[lane] + bp[lane]);
        sincosf(0.5f * h0, &mys0, &myc0);
        sincosf(0.5f * h1, &mys1, &myc1);
    }

    // ---- statevectors |0..0>: components = (state A, state B) ----
    f2 re[16], im[16];
#pragma unroll
    for (int r = 0; r < 16; r++) { re[r] = sp(0.f); im[r] = sp(0.f); }
    if (lane == 0) { re[0].x = 1.f; re[0].y = 1.f; }

    // Pull-index for the composite lane-CNOT chain: src_lane = Gray(lane)
    const int bidx = (lane ^ (lane >> 1)) << 2;

    // ---- layer 0: RY fused into Rot (per-state matrices packed as f2 components) ----
    {
        const float* gl = &gates[0];
#define FROTQ(Q, GATECALL) { \
        f2 cc, ss; \
        cc.x = __shfl(myc0, Q, 64); cc.y = __shfl(myc1, Q, 64); \
        ss.x = __shfl(mys0, Q, 64); ss.y = __shfl(mys1, Q, 64); \
        float4 gA = *(const float4*)(gl + Q * 8); \
        float4 gB = *(const float4*)(gl + Q * 8 + 4); \
        G2 g; \
        g.Ax = gA.x * cc + gA.z * ss;  g.Ay = gA.y * cc + gA.w * ss; \
        g.Az = gA.z * cc - gA.x * ss;  g.Aw = gA.w * cc - gA.y * ss; \
        g.Bx = gB.x * cc + gB.z * ss;  g.By = gB.y * cc + gB.w * ss; \
        g.Bz = gB.z * cc - gB.x * ss;  g.Bw = gB.w * cc - gB.y * ss; \
        GATECALL; }
        FROTQ(0, (rot_gate_pl_c<32>(re, im, g)))        // P=9
        FROTQ(1, (rot_gate_pl_c<16>(re, im, g)))        // P=8
        FROTQ(2, (rot_gate_c<7>(re, im, lane, g)))
        FROTQ(3, (rot_gate_c<6>(re, im, lane, g)))
        FROTQ(4, (rot_gate_c<5>(re, im, lane, g)))
        FROTQ(5, (rot_gate_c<4>(re, im, lane, g)))
        FROTQ(6, (rot_gate_c<3>(re, im, lane, g)))
        FROTQ(7, (rot_gate_c<2>(re, im, lane, g)))
        FROTQ(8, (rot_gate_c<1>(re, im, lane, g)))
        FROTQ(9, (rot_gate_c<0>(re, im, lane, g)))
#undef FROTQ
        // CNOT ring (9,8)..(5,4) as one lane permutation
#pragma unroll
        for (int r = 0; r < 16; r++) {
            re[r].x = __int_as_float(__builtin_amdgcn_ds_bpermute(bidx, __float_as_int(re[r].x)));
            re[r].y = __int_as_float(__builtin_amdgcn_ds_bpermute(bidx, __float_as_int(re[r].y)));
            im[r].x = __int_as_float(__builtin_amdgcn_ds_bpermute(bidx, __float_as_int(im[r].x)));
            im[r].y = __int_as_float(__builtin_amdgcn_ds_bpermute(bidx, __float_as_int(im[r].y)));
        }
        cnot_gate_c<4, 3>(re, im, lane);
        cnot_gate_c<3, 2>(re, im, lane);
        cnot_gate_c<2, 1>(re, im, lane);
        cnot_gate_c<1, 0>(re, im, lane);
        // cnot<0,9> fused into next layer's rot<9>
    }

    // ---- layers 1..3 (first gate consumes previous layer's trailing cnot<0,9>) ----
    for (int l = 1; l < NLAYERS; l++) {
        const float* gl = &gates[l * NQ * 8];
        { G2 g = load_g(gl, 0); rot9_fused_c(re, im, lane, g); }
        { G2 g = load_g(gl, 1); rot_gate_pl_c<16>(re, im, g); }   // P=8
        { G2 g = load_g(gl, 2); rot_gate_c<7>(re, im, lane, g); }
        { G2 g = load_g(gl, 3); rot_gate_c<6>(re, im, lane, g); }
        { G2 g = load_g(gl, 4); rot_gate_c<5>(re, im, lane, g); }
        { G2 g = load_g(gl, 5); rot_gate_c<4>(re, im, lane, g); }
        { G2 g = load_g(gl, 6); rot_gate_c<3>(re, im, lane, g); }
        { G2 g = load_g(gl, 7); rot_gate_c<2>(re, im, lane, g); }
        { G2 g = load_g(gl, 8); rot_gate_c<1>(re, im, lane, g); }
        { G2 g = load_g(gl, 9); rot_gate_c<0>(re, im, lane, g); }
#pragma unroll
        for (int r = 0; r < 16; r++) {
            re[r].x = __int_as_float(__builtin_amdgcn_ds_bpermute(bidx, __float_as_int(re[r].x)));
            re[r].y = __int_as_float(__builtin_amdgcn_ds_bpermute(bidx, __float_as_int(re[r].y)));
            im[r].x = __int_as_float(__builtin_amdgcn_ds_bpermute(bidx, __float_as_int(im[r].x)));
            im[r].y = __int_as_float(__builtin_amdgcn_ds_bpermute(bidx, __float_as_int(im[r].y)));
        }
        cnot_gate_c<4, 3>(re, im, lane);
        cnot_gate_c<3, 2>(re, im, lane);
        cnot_gate_c<2, 1>(re, im, lane);
        cnot_gate_c<1, 0>(re, im, lane);
    }
    // layer 3's trailing cnot<0,9> applied for real (measurement follows)
    cnot_gate_c<0, 9>(re, im, lane);

    // ---- measurement: Z expectation per qubit, both states packed ----
    f2 S = sp(0.f), z3 = sp(0.f), z2 = sp(0.f), z1 = sp(0.f), z0 = sp(0.f);
#pragma unroll
    for (int r = 0; r < 16; r++) {
        f2 pa = re[r] * re[r] + im[r] * im[r];
        S += pa;
        if (r & 8) z3 -= pa; else z3 += pa;
        if (r & 4) z2 -= pa; else z2 += pa;
        if (r & 2) z1 -= pa; else z1 += pa;
        if (r & 1) z0 -= pa; else z0 += pa;
    }
    f2 zq[NQ];
    zq[6] = z3; zq[7] = z2; zq[8] = z1; zq[9] = z0;
#pragma unroll
    for (int q = 0; q < 6; q++) {                      // lane qubits: lane bit 5-q
        zq[q] = ((lane >> (5 - q)) & 1) ? -S : S;
    }
#pragma unroll
    for (int q = 0; q < NQ; q++) {
#pragma unroll
        for (int o = 1; o < 64; o <<= 1) {
            zq[q].x += __shfl_xor(zq[q].x, o, 64);
            zq[q].y += __shfl_xor(zq[q].y, o, 64);
        }
    }

    // ---- output projection: out = zq @ Wo^T + bo, both states ----
    if (lane < NQ) {
        const float* wrow = Wo + lane * NQ;
        float o0 = bo[lane], o1 = o0;
#pragma unroll
        for (int q = 0; q < NQ; q++) {
            float w = wrow[q];
            o0 += zq[q].x * w;
            o1 += zq[q].y * w;
        }
        out[(size_t)s0 * NQ + lane] = o0;
        out[(size_t)s1 * NQ + lane] = o1;
    }
}

extern "C" void kernel_launch(void* const* d_in, const int* in_sizes, int n_in,
                              void* d_out, int out_size, void* d_ws, size_t ws_size,
                              hipStream_t stream) {
    const float* x  = (const float*)d_in[0];
    const float* Wp = (const float*)d_in[1];
    const float* bp = (const float*)d_in[2];
    const float* qw = (const float*)d_in[3];
    const float* Wo = (const float*)d_in[4];
    const float* bo = (const float*)d_in[5];
    float* out = (float*)d_out;

    const int B = in_sizes[0] / D_IN;                  // 8192 states, two per wave
    const int waves = (B + 1) / 2;
    const int spb = BLOCK / 64;                        // waves per block (4)
    const int blocks = (waves + spb - 1) / spb;
    hipLaunchKernelGGL(qnet_kernel, dim3(blocks), dim3(BLOCK), 0, stream,
                       x, Wp, bp, qw, Wo, bo, out, B);
}

// Round 5
// 147.154 us; speedup vs baseline: 1.0187x; 1.0187x over previous
//
#include <hip/hip_runtime.h>

#define NQ      10
#define NLAYERS 4
#define D_IN    784
#define BLOCK   256   // 4 waves per workgroup, ONE state per wave, amp-pair pk packing.
// R17: R16 showed dur is (VALU stream)/(busy%), busy stuck at 55% because 2-states/wave
// halves wave supply (4096). Per-state VALU cost is ~equal for 1- vs 2-state layouts, so:
// 1 state/wave (8192 waves, R14's 76% busy regime) + KEEP pk math by packing f2 components
// with two adjacent amps (bit0) of the SAME state: re[8], im[8].
// Qubit->bit map: q0..q5 = lane bits 32,16,8,4,2,1; q6..q8 = array-index bits 4,2,1; q9 = f2 component.
// Pipe per gate: q0 permlane32_swap, q1 permlane16_swap, q2 DPP row_ror:8 (NEW, was DS),
// q3 shfl_xor4 (only DS gate), q4/q5 quad_perm DPP, q6-q8 pure pk, q9 component-swap pk.
// Ring: lane-chain CNOTs -> one Gray bpermute; (5,6) cndmask; (6,7),(7,8) renames;
// (8,9) component swap; (9,0) FOLDED into next layer's rot0 coefficients / measurement signs.
// DS ops/wave: ~1300 -> ~420.
// Tripwire: WRITE_SIZE ~0.3 MB (spill); if busy stays ~55% at 8192 waves, chain latency
// is the floor -> next round interleaves independent work, not occupancy.
// LOCKED: reductions use plain __shfl_xor only (R8 DPP reductions diverged across graph
// replays). DPP confined to full-exec lane exchanges (stable since R4).

typedef __attribute__((ext_vector_type(2))) float f2;

__device__ __forceinline__ f2 swapc(f2 v) { return __builtin_shufflevector(v, v, 1, 0); }

// ---- lane exchange: xor LB, VALU pipe where possible ----
template<int LB>
__device__ __forceinline__ float lx(float v) {
    if constexpr (LB == 1) {        // quad_perm [1,0,3,2]
        return __int_as_float(__builtin_amdgcn_update_dpp(
            0, __float_as_int(v), 0xB1, 0xF, 0xF, false));
    } else if constexpr (LB == 2) { // quad_perm [2,3,0,1]
        return __int_as_float(__builtin_amdgcn_update_dpp(
            0, __float_as_int(v), 0x4E, 0xF, 0xF, false));
    } else if constexpr (LB == 8) { // row_ror:8 within 16 == xor 8 (VALU)
        return __int_as_float(__builtin_amdgcn_update_dpp(
            0, __float_as_int(v), 0x128, 0xF, 0xF, false));
    } else {
        return __shfl_xor(v, LB, 64);   // LB==4: DS pipe (no VALU equivalent)
    }
}

template<int LB>
__device__ __forceinline__ f2 lx2(f2 v) {
    f2 r; r.x = lx<LB>(v.x); r.y = lx<LB>(v.y); return r;
}

// ---- permlane pair swap (VALU pipe) ----
template<int HALF>
__device__ __forceinline__ void plswap(f2 &d, f2 &s) {
    if constexpr (HALF == 32) {
        auto rx = __builtin_amdgcn_permlane32_swap(__float_as_int(d.x), __float_as_int(s.x), false, false);
        auto ry = __builtin_amdgcn_permlane32_swap(__float_as_int(d.y), __float_as_int(s.y), false, false);
        d.x = __int_as_float(rx[0]); s.x = __int_as_float(rx[1]);
        d.y = __int_as_float(ry[0]); s.y = __int_as_float(ry[1]);
    } else {
        auto rx = __builtin_amdgcn_permlane16_swap(__float_as_int(d.x), __float_as_int(s.x), false, false);
        auto ry = __builtin_amdgcn_permlane16_swap(__float_as_int(d.y), __float_as_int(s.y), false, false);
        d.x = __int_as_float(rx[0]); s.x = __int_as_float(rx[1]);
        d.y = __int_as_float(ry[0]); s.y = __int_as_float(ry[1]);
    }
}

// ---- Rot on lane bit 32 or 16 via permlane pair-processing (proven R15/R16 pattern) ----
template<int HALF>
__device__ __forceinline__ void rot_pl(f2 (&re)[8], f2 (&im)[8], float4 A, float4 B) {
#pragma unroll
    for (int a = 0; a < 8; a += 2) {
        f2 ur = re[a], vr = re[a + 1], ui = im[a], vi = im[a + 1];
        plswap<HALF>(ur, vr); plswap<HALF>(ui, vi);
        f2 nur = A.x*ur - A.y*ui + A.z*vr - A.w*vi;
        f2 nui = A.x*ui + A.y*ur + A.z*vi + A.w*vr;
        f2 nvr = B.x*ur - B.y*ui + B.z*vr - B.w*vi;
        f2 nvi = B.x*ui + B.y*ur + B.z*vi + B.w*vr;
        plswap<HALF>(nur, nvr); plswap<HALF>(nui, nvi);
        re[a] = nur; re[a + 1] = nvr; im[a] = nui; im[a + 1] = nvi;
    }
}

// ---- rot on q0 (lane bit 32) with PREVIOUS layer's CNOT(ctrl=component, tgt=bit32)
// folded into per-component coefficient packing (coeffs lane-uniform -> safe w/ plswap) ----
__device__ __forceinline__ void rot0_fused(f2 (&re)[8], f2 (&im)[8], float4 A, float4 B) {
    f2 CuAr, CuAi, CvAr, CvAi, CuBr, CuBi, CvBr, CvBi;
    CuAr.x = A.x; CuAr.y = A.z;   CuAi.x = A.y; CuAi.y = A.w;
    CvAr.x = A.z; CvAr.y = A.x;   CvAi.x = A.w; CvAi.y = A.y;
    CuBr.x = B.x; CuBr.y = B.z;   CuBi.x = B.y; CuBi.y = B.w;
    CvBr.x = B.z; CvBr.y = B.x;   CvBi.x = B.w; CvBi.y = B.y;
#pragma unroll
    for (int a = 0; a < 8; a += 2) {
        f2 ur = re[a], vr = re[a + 1], ui = im[a], vi = im[a + 1];
        plswap<32>(ur, vr); plswap<32>(ui, vi);
        f2 nur = CuAr*ur - CuAi*ui + CvAr*vr - CvAi*vi;
        f2 nui = CuAr*ui + CuAi*ur + CvAr*vi + CvAi*vr;
        f2 nvr = CuBr*ur - CuBi*ui + CvBr*vr - CvBi*vi;
        f2 nvi = CuBr*ui + CuBi*ur + CvBr*vi + CvBi*vr;
        plswap<32>(nur, nvr); plswap<32>(nui, nvi);
        re[a] = nur; re[a + 1] = nvr; im[a] = nui; im[a + 1] = nvi;
    }
}

// ---- Rot on lane bit LB (8,4,2,1) via xor exchange, hi/lo coefficient select ----
template<int LB>
__device__ __forceinline__ void rot_lane(f2 (&re)[8], f2 (&im)[8], int lane, float4 A, float4 B) {
    const bool hi = (lane & LB) != 0;
    const float gdx = hi ? B.z : A.x, gdy = hi ? B.w : A.y;   // diagonal
    const float gox = hi ? B.x : A.z, goy = hi ? B.y : A.w;   // off-diagonal
#pragma unroll
    for (int a = 0; a < 8; a++) {
        f2 ore = lx2<LB>(re[a]);
        f2 oim = lx2<LB>(im[a]);
        f2 vr = re[a], vi = im[a];
        re[a] = gdx*vr - gdy*vi + gox*ore - goy*oim;
        im[a] = gdx*vi + gdy*vr + gox*oim + goy*ore;
    }
}

// ---- Rot on array-index bit MB (4,2,1): pure register pairing, pure pk ----
template<int MB>
__device__ __forceinline__ void rot_reg(f2 (&re)[8], f2 (&im)[8], float4 A, float4 B) {
#pragma unroll
    for (int a = 0; a < 8; a++) {
        if (!(a & MB)) {
            const int a1 = a | MB;
            f2 r0r = re[a], r0i = im[a], r1r = re[a1], r1i = im[a1];
            re[a]  = A.x*r0r - A.y*r0i + A.z*r1r - A.w*r1i;
            im[a]  = A.x*r0i + A.y*r0r + A.z*r1i + A.w*r1r;
            re[a1] = B.x*r0r - B.y*r0i + B.z*r1r - B.w*r1i;
            im[a1] = B.x*r0i + B.y*r0r + B.z*r1i + B.w*r1r;
        }
    }
}

// ---- Rot on the f2 component bit (q9): coefficient-packed, 2 swaps + 8 pk per reg ----
__device__ __forceinline__ void rot_comp(f2 (&re)[8], f2 (&im)[8], float4 A, float4 B) {
    f2 K1, K2, K3, K4;
    K1.x = A.x; K1.y = B.z;   K2.x = -A.y; K2.y = -B.w;
    K3.x = A.z; K3.y = B.x;   K4.x = -A.w; K4.y = -B.y;
#pragma unroll
    for (int a = 0; a < 8; a++) {
        f2 sre = swapc(re[a]), sim = swapc(im[a]);
        f2 nre = K1*re[a] + K2*im[a] + K3*sre + K4*sim;
        f2 nim = K1*im[a] - K2*re[a] + K3*sim - K4*sre;
        re[a] = nre; im[a] = nim;
    }
}

__device__ __forceinline__ void swapf2(f2 &a, f2 &b) { f2 t = a; a = b; b = t; }

// ---- CNOT ring: Gray bpermute (q0..q5 chain), (5,6) cndmask, renames, (8,9) comp swap.
// (9,0) is NOT applied here: folded into next layer's rot0_fused / measurement signs. ----
__device__ __forceinline__ void ring(f2 (&re)[8], f2 (&im)[8], int lane, int bidx) {
#pragma unroll
    for (int a = 0; a < 8; a++) {
        re[a].x = __int_as_float(__builtin_amdgcn_ds_bpermute(bidx, __float_as_int(re[a].x)));
        re[a].y = __int_as_float(__builtin_amdgcn_ds_bpermute(bidx, __float_as_int(re[a].y)));
        im[a].x = __int_as_float(__builtin_amdgcn_ds_bpermute(bidx, __float_as_int(im[a].x)));
        im[a].y = __int_as_float(__builtin_amdgcn_ds_bpermute(bidx, __float_as_int(im[a].y)));
    }
    // (5,6): ctrl = lane bit 0, target = array bit 4 (swap a <-> a+4)
    const bool ctl = (lane & 1) != 0;
#pragma unroll
    for (int a = 0; a < 4; a++) {
        f2 A0 = re[a], A1 = re[a + 4], B0 = im[a], B1 = im[a + 4];
        f2 n0, n1, m0, m1;
        n0.x = ctl ? A1.x : A0.x;  n0.y = ctl ? A1.y : A0.y;
        n1.x = ctl ? A0.x : A1.x;  n1.y = ctl ? A0.y : A1.y;
        m0.x = ctl ? B1.x : B0.x;  m0.y = ctl ? B1.y : B0.y;
        m1.x = ctl ? B0.x : B1.x;  m1.y = ctl ? B0.y : B1.y;
        re[a] = n0; re[a + 4] = n1; im[a] = m0; im[a + 4] = m1;
    }
    // (6,7): ctrl array bit 4, tgt bit 2: free renames
    swapf2(re[4], re[6]); swapf2(re[5], re[7]); swapf2(im[4], im[6]); swapf2(im[5], im[7]);
    // (7,8): ctrl array bit 2, tgt bit 1
    swapf2(re[2], re[3]); swapf2(re[6], re[7]); swapf2(im[2], im[3]); swapf2(im[6], im[7]);
    // (8,9): ctrl array bit 1, tgt component: swap components for odd a
#pragma unroll
    for (int a = 1; a < 8; a += 2) { re[a] = swapc(re[a]); im[a] = swapc(im[a]); }
}

__global__ __launch_bounds__(BLOCK)
__attribute__((amdgpu_waves_per_eu(2, 8)))
void qnet_kernel(
    const float* __restrict__ x,
    const float* __restrict__ Wp,
    const float* __restrict__ bp,
    const float* __restrict__ qw,
    const float* __restrict__ Wo,
    const float* __restrict__ bo,
    float* __restrict__ out, int B)
{
    __shared__ __align__(16) float gates[NLAYERS * NQ * 8];  // per-WG Rot matrix table

    const int tid  = threadIdx.x;
    const int lane = tid & 63;
    const int s    = blockIdx.x * (BLOCK / 64) + (tid >> 6);   // one state per wave

    // ---- Rot gate table (built once per workgroup, shared by 4 waves) ----
    if (tid < NLAYERS * NQ) {
        float phi = qw[tid * 3 + 0];
        float th  = qw[tid * 3 + 1];
        float om  = qw[tid * 3 + 2];
        float sth, cth; sincosf(0.5f * th, &sth, &cth);
        float sap, cap; sincosf(0.5f * (phi + om), &sap, &cap);
        float sam, cam; sincosf(0.5f * (phi - om), &sam, &cam);
        float* g = &gates[tid * 8];
        g[0] =  cap * cth;  g[1] = -sap * cth;   // u00
        g[2] = -cam * sth;  g[3] = -sam * sth;   // u01
        g[4] =  cam * sth;  g[5] = -sam * sth;   // u10
        g[6] =  cap * cth;  g[7] =  sap * cth;   // u11
    }
    __syncthreads();
    if (s >= B) return;

    // ---- projection (float4: 784 = 3*256 + 16) ----
    float acc[NQ];
#pragma unroll
    for (int q = 0; q < NQ; q++) acc[q] = 0.f;
    const float* xr = x + (size_t)s * D_IN;
#pragma unroll
    for (int it = 0; it < 3; it++) {
        const int d = (it * 64 + lane) * 4;
        float4 xv = *(const float4*)(xr + d);
#pragma unroll
        for (int q = 0; q < NQ; q++) {
            float4 wv = *(const float4*)(Wp + q * D_IN + d);
            acc[q] += xv.x * wv.x + xv.y * wv.y + xv.z * wv.z + xv.w * wv.w;
        }
    }
    if (lane < 4) {                                    // tail 768..783
        const int d = (192 + lane) * 4;
        float4 xv = *(const float4*)(xr + d);
#pragma unroll
        for (int q = 0; q < NQ; q++) {
            float4 wv = *(const float4*)(Wp + q * D_IN + d);
            acc[q] += xv.x * wv.x + xv.y * wv.y + xv.z * wv.z + xv.w * wv.w;
        }
    }
#pragma unroll
    for (int q = 0; q < NQ; q++) {
#pragma unroll
        for (int o = 1; o < 64; o <<= 1) acc[q] += __shfl_xor(acc[q], o, 64);
    }
    float myc = 1.f, mys = 0.f;
    if (lane < NQ) {
        float h = tanhf(acc[lane] + bp[lane]);
        sincosf(0.5f * h, &mys, &myc);
    }

    // ---- statevector |0..0>: re/im[8] f2, component = amp bit 0 ----
    f2 re[8], im[8];
#pragma unroll
    for (int a = 0; a < 8; a++) { re[a].x = 0.f; re[a].y = 0.f; im[a].x = 0.f; im[a].y = 0.f; }
    if (lane == 0) re[0].x = 1.f;

    const int bidx = (lane ^ (lane >> 1)) << 2;        // Gray pull for lane CNOT chain

    // ---- layer 0: RY fused into Rot (per-state matrices, RY angles via shfl bcast) ----
    {
        const float* gl = &gates[0];
#define MKMAT(Q) \
        float c0 = __shfl(myc, Q, 64), s0 = __shfl(mys, Q, 64); \
        float4 gA = *(const float4*)(gl + Q * 8); \
        float4 gB = *(const float4*)(gl + Q * 8 + 4); \
        float4 Am, Bm; \
        Am.x = gA.x * c0 + gA.z * s0;  Am.y = gA.y * c0 + gA.w * s0; \
        Am.z = gA.z * c0 - gA.x * s0;  Am.w = gA.w * c0 - gA.y * s0; \
        Bm.x = gB.x * c0 + gB.z * s0;  Bm.y = gB.y * c0 + gB.w * s0; \
        Bm.z = gB.z * c0 - gB.x * s0;  Bm.w = gB.w * c0 - gB.y * s0;
        { MKMAT(0); rot_pl<32>(re, im, Am, Bm); }
        { MKMAT(1); rot_pl<16>(re, im, Am, Bm); }
        { MKMAT(2); rot_lane<8>(re, im, lane, Am, Bm); }
        { MKMAT(3); rot_lane<4>(re, im, lane, Am, Bm); }
        { MKMAT(4); rot_lane<2>(re, im, lane, Am, Bm); }
        { MKMAT(5); rot_lane<1>(re, im, lane, Am, Bm); }
        { MKMAT(6); rot_reg<4>(re, im, Am, Bm); }
        { MKMAT(7); rot_reg<2>(re, im, Am, Bm); }
        { MKMAT(8); rot_reg<1>(re, im, Am, Bm); }
        { MKMAT(9); rot_comp(re, im, Am, Bm); }
#undef MKMAT
        ring(re, im, lane, bidx);     // (9,0) pending -> consumed by next rot0_fused
    }

    // ---- layers 1..3 ----
    for (int l = 1; l < NLAYERS; l++) {
        const float* gl = &gates[l * NQ * 8];
#define GMAT(Q) *(const float4*)(gl + Q * 8), *(const float4*)(gl + Q * 8 + 4)
        rot0_fused(re, im, GMAT(0));              // consumes pending (9,0)
        rot_pl<16>(re, im, GMAT(1));
        rot_lane<8>(re, im, lane, GMAT(2));
        rot_lane<4>(re, im, lane, GMAT(3));
        rot_lane<2>(re, im, lane, GMAT(4));
        rot_lane<1>(re, im, lane, GMAT(5));
        rot_reg<4>(re, im, GMAT(6));
        rot_reg<2>(re, im, GMAT(7));
        rot_reg<1>(re, im, GMAT(8));
        rot_comp(re, im, GMAT(9));
#undef GMAT
        ring(re, im, lane, bidx);     // (9,0) pending again
    }
    // Final pending (9,0) CNOT folded into measurement sign masks below.

    // ---- measurement: Z expectation per qubit ----
    // p per f2 keeps components separate; (9,0): effective bit32 for comp y is flipped.
    f2 S2 = {0.f, 0.f}, z62 = {0.f, 0.f}, z72 = {0.f, 0.f}, z82 = {0.f, 0.f};
#pragma unroll
    for (int a = 0; a < 8; a++) {
        f2 p = re[a] * re[a] + im[a] * im[a];
        S2 += p;
        if (a & 4) z62 -= p; else z62 += p;
        if (a & 2) z72 -= p; else z72 += p;
        if (a & 1) z82 -= p; else z82 += p;
    }
    const float Ssum = S2.x + S2.y;
    const float Sdif = S2.x - S2.y;
    float zq[NQ];
    zq[0] = (lane & 32) ? -Sdif : Sdif;   // q0: lane bit32 XOR component (folded CNOT)
    zq[1] = (lane & 16) ? -Ssum : Ssum;
    zq[2] = (lane &  8) ? -Ssum : Ssum;
    zq[3] = (lane &  4) ? -Ssum : Ssum;
    zq[4] = (lane &  2) ? -Ssum : Ssum;
    zq[5] = (lane &  1) ? -Ssum : Ssum;
    zq[6] = z62.x + z62.y;
    zq[7] = z72.x + z72.y;
    zq[8] = z82.x + z82.y;
    zq[9] = Sdif;                          // q9: component bit (untouched by folded CNOT)
#pragma unroll
    for (int q = 0; q < NQ; q++) {
#pragma unroll
        for (int o = 1; o < 64; o <<= 1) zq[q] += __shfl_xor(zq[q], o, 64);
    }

    // ---- output projection: out = zq @ Wo^T + bo ----
    if (lane < NQ) {
        const float* wrow = Wo + lane * NQ;
        float o0 = bo[lane];
#pragma unroll
        for (int q = 0; q < NQ; q++) o0 += zq[q] * wrow[q];
        out[(size_t)s * NQ + lane] = o0;
    }
}

extern "C" void kernel_launch(void* const* d_in, const int* in_sizes, int n_in,
                              void* d_out, int out_size, void* d_ws, size_t ws_size,
                              hipStream_t stream) {
    const float* x  = (const float*)d_in[0];
    const float* Wp = (const float*)d_in[1];
    const float* bp = (const float*)d_in[2];
    const float* qw = (const float*)d_in[3];
    const float* Wo = (const float*)d_in[4];
    const float* bo = (const float*)d_in[5];
    float* out = (float*)d_out;

    const int B = in_sizes[0] / D_IN;                  // 8192 states, one per wave
    const int spb = BLOCK / 64;                        // states per block (4)
    const int blocks = (B + spb - 1) / spb;
    hipLaunchKernelGGL(qnet_kernel, dim3(blocks), dim3(BLOCK), 0, stream,
                       x, Wp, bp, qw, Wo, bo, out, B);
}

// Round 6
// 139.584 us; speedup vs baseline: 1.0739x; 1.0542x over previous
//
#include <hip/hip_runtime.h>

#define NQ      10
#define NLAYERS 4
#define D_IN    784
#define BLOCK   256   // 4 waves per workgroup, ONE state per wave, amp-pair pk packing.
// R18: ALGEBRAIC cut. R15-R17 all land 91-94us: kernel is pinned by VALU stream length
// (~9.7k instr/state); pipe-shuffling is zero-sum. Factor each layer:
//   prod_q Rot_q(phi,theta,omega) = D_omega * (prod_q RY_q(theta)) * D_phi
// (single-qubit ops on distinct qubits commute). RY is REAL -> per-gate math halves
// (32 pk vs 64). Each diagonal = 1 complex mul/amp, separable lane-phase (1 sincos/layer)
// x reg-phase (16-entry LDS table per layer, built once per WG). Last layer's D_omega
// SKIPPED (diagonals don't change |amp|^2; trailing ring is a permutation). Layer-0
// embedding RYs -> direct product-state init (state is real & separable). Pending ring
// CNOT(q9->q0) folds into D_phi (comp-XOR sign on phi0 lane term) + coefficient-packed
// real q0-RY (R17 rot0_fused pattern re-derived for real coeffs).
// Hand count ~3.9k instr/state vs 9.7k measured in R17.
// Tripwire: WRITE_SIZE ~0.3 MB (spill). absmax should stay ~0.004 (exact reordering).
// If dur >=85us with clean counters: f2->v_pk lowering assumption wrong -> inline-asm
// v_pk_fma_f32 next.
// LOCKED: reductions use plain __shfl_xor only (R8 DPP reductions diverged across graph
// replays). DPP confined to full-exec lane exchanges (stable since R4).

// Amplitude index i (10 bits): lane bits 9..4 (q0..q5 = lane&32..lane&1),
// array-index bits 3..1 (q6,q7,q8 = a&4,a&2,a&1), component bit 0 (q9 = f2 comp).

typedef __attribute__((ext_vector_type(2))) float f2;

__device__ __forceinline__ f2 sp(float v) { f2 r; r.x = v; r.y = v; return r; }
__device__ __forceinline__ f2 swapc(f2 v) { return __builtin_shufflevector(v, v, 1, 0); }

// ---- lane exchange: xor LB, VALU pipe where possible ----
template<int LB>
__device__ __forceinline__ float lx(float v) {
    if constexpr (LB == 1) {        // quad_perm [1,0,3,2]
        return __int_as_float(__builtin_amdgcn_update_dpp(
            0, __float_as_int(v), 0xB1, 0xF, 0xF, false));
    } else if constexpr (LB == 2) { // quad_perm [2,3,0,1]
        return __int_as_float(__builtin_amdgcn_update_dpp(
            0, __float_as_int(v), 0x4E, 0xF, 0xF, false));
    } else if constexpr (LB == 8) { // row_ror:8 within 16 == xor 8 (VALU)
        return __int_as_float(__builtin_amdgcn_update_dpp(
            0, __float_as_int(v), 0x128, 0xF, 0xF, false));
    } else {
        return __shfl_xor(v, LB, 64);   // LB==4: DS pipe (no VALU equivalent)
    }
}

template<int LB>
__device__ __forceinline__ f2 lx2(f2 v) {
    f2 r; r.x = lx<LB>(v.x); r.y = lx<LB>(v.y); return r;
}

// ---- permlane pair swap (VALU pipe) ----
template<int HALF>
__device__ __forceinline__ void plswap(f2 &d, f2 &s) {
    if constexpr (HALF == 32) {
        auto rx = __builtin_amdgcn_permlane32_swap(__float_as_int(d.x), __float_as_int(s.x), false, false);
        auto ry = __builtin_amdgcn_permlane32_swap(__float_as_int(d.y), __float_as_int(s.y), false, false);
        d.x = __int_as_float(rx[0]); s.x = __int_as_float(rx[1]);
        d.y = __int_as_float(ry[0]); s.y = __int_as_float(ry[1]);
    } else {
        auto rx = __builtin_amdgcn_permlane16_swap(__float_as_int(d.x), __float_as_int(s.x), false, false);
        auto ry = __builtin_amdgcn_permlane16_swap(__float_as_int(d.y), __float_as_int(s.y), false, false);
        d.x = __int_as_float(rx[0]); s.x = __int_as_float(rx[1]);
        d.y = __int_as_float(ry[0]); s.y = __int_as_float(ry[1]);
    }
}

// ---- real RY on lane bit 32/16 via permlane pair-processing ----
template<int HALF>
__device__ __forceinline__ void ry_pl(f2 (&re)[8], f2 (&im)[8], float c, float s) {
#pragma unroll
    for (int a = 0; a < 8; a += 2) {
        f2 ur = re[a], vr = re[a + 1], ui = im[a], vi = im[a + 1];
        plswap<HALF>(ur, vr); plswap<HALF>(ui, vi);
        f2 nur = sp(c)*ur - sp(s)*vr;   f2 nui = sp(c)*ui - sp(s)*vi;
        f2 nvr = sp(s)*ur + sp(c)*vr;   f2 nvi = sp(s)*ui + sp(c)*vi;
        plswap<HALF>(nur, nvr); plswap<HALF>(nui, nvi);
        re[a] = nur; re[a + 1] = nvr; im[a] = nui; im[a + 1] = nvi;
    }
}

// ---- real RY on q0 (lane bit 32) with pending CNOT(ctrl=comp, tgt=bit32) consumed.
// After plswap every lane holds (u=amp(b0=0), v=amp(b0=1)); comp1 sees the pair
// pre-swapped by the CNOT -> coefficient-packed f2 constants. ----
__device__ __forceinline__ void ry0_fused(f2 (&re)[8], f2 (&im)[8], float c, float s) {
    f2 K1, K2, K3, K4;
    K1.x =  c; K1.y = -s;   K2.x = -s; K2.y =  c;
    K3.x =  s; K3.y =  c;   K4.x =  c; K4.y =  s;
#pragma unroll
    for (int a = 0; a < 8; a += 2) {
        f2 ur = re[a], vr = re[a + 1], ui = im[a], vi = im[a + 1];
        plswap<32>(ur, vr); plswap<32>(ui, vi);
        f2 nur = K1*ur + K2*vr;   f2 nui = K1*ui + K2*vi;
        f2 nvr = K3*ur + K4*vr;   f2 nvi = K3*ui + K4*vi;
        plswap<32>(nur, nvr); plswap<32>(nui, nvi);
        re[a] = nur; re[a + 1] = nvr; im[a] = nui; im[a + 1] = nvi;
    }
}

// ---- real RY on lane bit LB (8,4,2,1): exchange + 4 pk per reg ----
template<int LB>
__device__ __forceinline__ void ry_lane(f2 (&re)[8], f2 (&im)[8], int lane, float c, float s) {
    const float o = (lane & LB) ? s : -s;   // lo: u' = c*u - s*v ; hi: v' = c*v + s*u
#pragma unroll
    for (int a = 0; a < 8; a++) {
        f2 ore = lx2<LB>(re[a]);
        f2 oim = lx2<LB>(im[a]);
        re[a] = sp(c)*re[a] + sp(o)*ore;
        im[a] = sp(c)*im[a] + sp(o)*oim;
    }
}

// ---- real RY on array-index bit MB (4,2,1): 8 pk per pair ----
template<int MB>
__device__ __forceinline__ void ry_reg(f2 (&re)[8], f2 (&im)[8], float c, float s) {
#pragma unroll
    for (int a = 0; a < 8; a++) {
        if (!(a & MB)) {
            const int a1 = a | MB;
            f2 r0 = re[a], r1 = re[a1], i0 = im[a], i1 = im[a1];
            re[a]  = sp(c)*r0 - sp(s)*r1;   re[a1] = sp(s)*r0 + sp(c)*r1;
            im[a]  = sp(c)*i0 - sp(s)*i1;   im[a1] = sp(s)*i0 + sp(c)*i1;
        }
    }
}

// ---- real RY on the component bit (q9): swapc + 4 pk per reg ----
__device__ __forceinline__ void ry_comp(f2 (&re)[8], f2 (&im)[8], float c, float s) {
    f2 Ks; Ks.x = -s; Ks.y = s;
#pragma unroll
    for (int a = 0; a < 8; a++) {
        f2 sre = swapc(re[a]), sim = swapc(im[a]);
        re[a] = sp(c)*re[a] + Ks*sre;
        im[a] = sp(c)*im[a] + Ks*sim;
    }
}

// ---- diagonal apply: per-amp factor = e^{i*lane_phase} * e^{i*reg_phase[a]}.
// XOR0: pending CNOT(q9->q0) folded in -> phi0 lane-term sign flips on component. ----
template<bool XOR0>
__device__ __forceinline__ void diag_apply(f2 (&re)[8], f2 (&im)[8], int lane,
                                           const float* lz, const f2* DC, const f2* DS) {
    float lp = 0.f;
    lp += (lane & 16) ? lz[1] : -lz[1];
    lp += (lane &  8) ? lz[2] : -lz[2];
    lp += (lane &  4) ? lz[3] : -lz[3];
    lp += (lane &  2) ? lz[4] : -lz[4];
    lp += (lane &  1) ? lz[5] : -lz[5];
    const float t0 = (lane & 32) ? lz[0] : -lz[0];
    f2 cl, sl;
    if constexpr (XOR0) {
        float sa, ca, sb, cb;
        sincosf(lp + t0, &sa, &ca);
        sincosf(lp - t0, &sb, &cb);
        cl.x = ca; cl.y = cb; sl.x = sa; sl.y = sb;
    } else {
        float sa, ca;
        sincosf(lp + t0, &sa, &ca);
        cl = sp(ca); sl = sp(sa);
    }
#pragma unroll
    for (int a = 0; a < 8; a++) {
        f2 cr = cl*DC[a] - sl*DS[a];      // combined complex coefficient
        f2 ci = cl*DS[a] + sl*DC[a];
        f2 nr = cr*re[a] - ci*im[a];
        f2 ni = cr*im[a] + ci*re[a];
        re[a] = nr; im[a] = ni;
    }
}

__device__ __forceinline__ void swapf2(f2 &a, f2 &b) { f2 t = a; a = b; b = t; }

// ---- CNOT ring: Gray bpermute (q0..q5 chain), (5,6) cndmask, renames, (8,9) comp swap.
// (9,0) NOT applied: folded into next layer's D_phi/ry0_fused or measurement signs. ----
__device__ __forceinline__ void ring(f2 (&re)[8], f2 (&im)[8], int lane, int bidx) {
#pragma unroll
    for (int a = 0; a < 8; a++) {
        re[a].x = __int_as_float(__builtin_amdgcn_ds_bpermute(bidx, __float_as_int(re[a].x)));
        re[a].y = __int_as_float(__builtin_amdgcn_ds_bpermute(bidx, __float_as_int(re[a].y)));
        im[a].x = __int_as_float(__builtin_amdgcn_ds_bpermute(bidx, __float_as_int(im[a].x)));
        im[a].y = __int_as_float(__builtin_amdgcn_ds_bpermute(bidx, __float_as_int(im[a].y)));
    }
    const bool ctl = (lane & 1) != 0;      // (5,6): ctrl lane bit0, tgt array bit 4
#pragma unroll
    for (int a = 0; a < 4; a++) {
        f2 A0 = re[a], A1 = re[a + 4], B0 = im[a], B1 = im[a + 4];
        f2 n0, n1, m0, m1;
        n0.x = ctl ? A1.x : A0.x;  n0.y = ctl ? A1.y : A0.y;
        n1.x = ctl ? A0.x : A1.x;  n1.y = ctl ? A0.y : A1.y;
        m0.x = ctl ? B1.x : B0.x;  m0.y = ctl ? B1.y : B0.y;
        m1.x = ctl ? B0.x : B1.x;  m1.y = ctl ? B0.y : B1.y;
        re[a] = n0; re[a + 4] = n1; im[a] = m0; im[a + 4] = m1;
    }
    // (6,7): ctrl array bit 4, tgt bit 2: free renames
    swapf2(re[4], re[6]); swapf2(re[5], re[7]); swapf2(im[4], im[6]); swapf2(im[5], im[7]);
    // (7,8): ctrl array bit 2, tgt bit 1
    swapf2(re[2], re[3]); swapf2(re[6], re[7]); swapf2(im[2], im[3]); swapf2(im[6], im[7]);
    // (8,9): ctrl array bit 1, tgt component
#pragma unroll
    for (int a = 1; a < 8; a += 2) { re[a] = swapc(re[a]); im[a] = swapc(im[a]); }
}

__global__ __launch_bounds__(BLOCK)
__attribute__((amdgpu_waves_per_eu(2, 8)))
void qnet_kernel(
    const float* __restrict__ x,
    const float* __restrict__ Wp,
    const float* __restrict__ bp,
    const float* __restrict__ qw,
    const float* __restrict__ Wo,
    const float* __restrict__ bo,
    float* __restrict__ out, int B)
{
    // Per-WG tables:
    __shared__ float ryt[NLAYERS * NQ * 2];        // (l*10+q)*2: cos(th/2), sin(th/2)
    __shared__ float lzt[NLAYERS * 2 * 6];         // (l*2+t)*6+q: half-angles q0..q5 (t:0=phi,1=omega)
    __shared__ __align__(8) f2 dct[NLAYERS * 2 * 8];  // (l*2+t)*8+a: reg-diag cos (comp-packed)
    __shared__ __align__(8) f2 dst[NLAYERS * 2 * 8];  // reg-diag sin

    const int tid  = threadIdx.x;
    const int lane = tid & 63;
    const int s    = blockIdx.x * (BLOCK / 64) + (tid >> 6);   // one state per wave

    if (tid < NLAYERS * NQ) {                      // 40 threads: RY pairs + lane half-angles
        const int l = tid / NQ, q = tid % NQ;
        float th = qw[tid * 3 + 1];
        float sc, cc; sincosf(0.5f * th, &sc, &cc);
        ryt[tid * 2] = cc; ryt[tid * 2 + 1] = sc;
        if (q < 6) {
            lzt[(l * 2 + 0) * 6 + q] = 0.5f * qw[tid * 3 + 0];   // phi
            lzt[(l * 2 + 1) * 6 + q] = 0.5f * qw[tid * 3 + 2];   // omega
        }
    }
    if (tid >= 64 && tid < 128) {                  // 64 threads: reg-diag tables
        const int idx = tid - 64;
        const int l = idx >> 4, t = (idx >> 3) & 1, a = idx & 7;
        const float* ql = qw + (size_t)l * NQ * 3;
        const int off = t ? 2 : 0;
        const float p6 = 0.5f * ql[6 * 3 + off], p7 = 0.5f * ql[7 * 3 + off];
        const float p8 = 0.5f * ql[8 * 3 + off], p9 = 0.5f * ql[9 * 3 + off];
        const float base = ((a & 4) ? p6 : -p6) + ((a & 2) ? p7 : -p7) + ((a & 1) ? p8 : -p8);
        float s0, c0, s1, c1;
        sincosf(base - p9, &s0, &c0);              // comp 0: q9 bit = 0
        sincosf(base + p9, &s1, &c1);              // comp 1: q9 bit = 1
        f2 dc; dc.x = c0; dc.y = c1;
        f2 ds; ds.x = s0; ds.y = s1;
        dct[(l * 2 + t) * 8 + a] = dc;
        dst[(l * 2 + t) * 8 + a] = ds;
    }
    __syncthreads();
    if (s >= B) return;

    // ---- projection (float4: 784 = 3*256 + 16) ----
    float acc[NQ];
#pragma unroll
    for (int q = 0; q < NQ; q++) acc[q] = 0.f;
    const float* xr = x + (size_t)s * D_IN;
#pragma unroll
    for (int it = 0; it < 3; it++) {
        const int d = (it * 64 + lane) * 4;
        float4 xv = *(const float4*)(xr + d);
#pragma unroll
        for (int q = 0; q < NQ; q++) {
            float4 wv = *(const float4*)(Wp + q * D_IN + d);
            acc[q] += xv.x * wv.x + xv.y * wv.y + xv.z * wv.z + xv.w * wv.w;
        }
    }
    if (lane < 4) {                                // tail 768..783
        const int d = (192 + lane) * 4;
        float4 xv = *(const float4*)(xr + d);
#pragma unroll
        for (int q = 0; q < NQ; q++) {
            float4 wv = *(const float4*)(Wp + q * D_IN + d);
            acc[q] += xv.x * wv.x + xv.y * wv.y + xv.z * wv.z + xv.w * wv.w;
        }
    }
#pragma unroll
    for (int q = 0; q < NQ; q++) {
#pragma unroll
        for (int o = 1; o < 64; o <<= 1) acc[q] += __shfl_xor(acc[q], o, 64);
    }
    float myc = 1.f, mys = 0.f;
    if (lane < NQ) {
        float h = tanhf(acc[lane] + bp[lane]);
        sincosf(0.5f * h, &mys, &myc);
    }

    // ---- embedding: direct product-state init (all-real, separable) ----
    f2 re[8], im[8];
    float lf = 1.f;
    {
        float cq, sq;
#define SEL(Q, MASK) cq = __shfl(myc, Q, 64); sq = __shfl(mys, Q, 64); \
                     lf *= (lane & MASK) ? sq : cq;
        SEL(0, 32) SEL(1, 16) SEL(2, 8) SEL(3, 4) SEL(4, 2) SEL(5, 1)
#undef SEL
        const float c6 = __shfl(myc, 6, 64), s6 = __shfl(mys, 6, 64);
        const float c7 = __shfl(myc, 7, 64), s7 = __shfl(mys, 7, 64);
        const float c8 = __shfl(myc, 8, 64), s8 = __shfl(mys, 8, 64);
        const float c9 = __shfl(myc, 9, 64), s9 = __shfl(mys, 9, 64);
#pragma unroll
        for (int a = 0; a < 8; a++) {
            float t = ((a & 4) ? s6 : c6) * ((a & 2) ? s7 : c7) * ((a & 1) ? s8 : c8) * lf;
            re[a].x = t * c9; re[a].y = t * s9;
            im[a] = sp(0.f);
        }
    }

    const int bidx = (lane ^ (lane >> 1)) << 2;    // Gray pull for lane CNOT chain

    // ---- layer 0: D_phi, 10 RYs, D_omega, ring ----
    {
        const float* rl = ryt;
        diag_apply<false>(re, im, lane, lzt, dct, dst);                    // D_phi(0)
        ry_pl<32>(re, im, rl[0], rl[1]);
        ry_pl<16>(re, im, rl[2], rl[3]);
        ry_lane<8>(re, im, lane, rl[4], rl[5]);
        ry_lane<4>(re, im, lane, rl[6], rl[7]);
        ry_lane<2>(re, im, lane, rl[8], rl[9]);
        ry_lane<1>(re, im, lane, rl[10], rl[11]);
        ry_reg<4>(re, im, rl[12], rl[13]);
        ry_reg<2>(re, im, rl[14], rl[15]);
        ry_reg<1>(re, im, rl[16], rl[17]);
        ry_comp(re, im, rl[18], rl[19]);
        diag_apply<false>(re, im, lane, lzt + 6, dct + 8, dst + 8);        // D_omega(0)
        ring(re, im, lane, bidx);                  // leaves (9,0) pending
    }

    // ---- layers 1..3 ----
    for (int l = 1; l < NLAYERS; l++) {
        const float* rl = ryt + l * NQ * 2;
        diag_apply<true>(re, im, lane, lzt + (l * 2) * 6,
                         dct + (l * 2) * 8, dst + (l * 2) * 8);            // D'_phi (C folded)
        ry0_fused(re, im, rl[0], rl[1]);           // consumes pending C
        ry_pl<16>(re, im, rl[2], rl[3]);
        ry_lane<8>(re, im, lane, rl[4], rl[5]);
        ry_lane<4>(re, im, lane, rl[6], rl[7]);
        ry_lane<2>(re, im, lane, rl[8], rl[9]);
        ry_lane<1>(re, im, lane, rl[10], rl[11]);
        ry_reg<4>(re, im, rl[12], rl[13]);
        ry_reg<2>(re, im, rl[14], rl[15]);
        ry_reg<1>(re, im, rl[16], rl[17]);
        ry_comp(re, im, rl[18], rl[19]);
        if (l < NLAYERS - 1)                       // last D_omega skipped (|amp|^2 invariant)
            diag_apply<false>(re, im, lane, lzt + (l * 2 + 1) * 6,
                              dct + (l * 2 + 1) * 8, dst + (l * 2 + 1) * 8);
        ring(re, im, lane, bidx);                  // (9,0) pending again
    }
    // Final pending (9,0) CNOT folded into measurement sign masks below.

    // ---- measurement: Z expectation per qubit ----
    f2 S2 = {0.f, 0.f}, z62 = {0.f, 0.f}, z72 = {0.f, 0.f}, z82 = {0.f, 0.f};
#pragma unroll
    for (int a = 0; a < 8; a++) {
        f2 p = re[a] * re[a] + im[a] * im[a];
        S2 += p;
        if (a & 4) z62 -= p; else z62 += p;
        if (a & 2) z72 -= p; else z72 += p;
        if (a & 1) z82 -= p; else z82 += p;
    }
    const float Ssum = S2.x + S2.y;
    const float Sdif = S2.x - S2.y;
    float zq[NQ];
    zq[0] = (lane & 32) ? -Sdif : Sdif;   // q0: lane bit32 XOR component (folded CNOT)
    zq[1] = (lane & 16) ? -Ssum : Ssum;
    zq[2] = (lane &  8) ? -Ssum : Ssum;
    zq[3] = (lane &  4) ? -Ssum : Ssum;
    zq[4] = (lane &  2) ? -Ssum : Ssum;
    zq[5] = (lane &  1) ? -Ssum : Ssum;
    zq[6] = z62.x + z62.y;
    zq[7] = z72.x + z72.y;
    zq[8] = z82.x + z82.y;
    zq[9] = Sdif;                          // q9: component bit (untouched by folded CNOT)
#pragma unroll
    for (int q = 0; q < NQ; q++) {
#pragma unroll
        for (int o = 1; o < 64; o <<= 1) zq[q] += __shfl_xor(zq[q], o, 64);
    }

    // ---- output projection: out = zq @ Wo^T + bo ----
    if (lane < NQ) {
        const float* wrow = Wo + lane * NQ;
        float o0 = bo[lane];
#pragma unroll
        for (int q = 0; q < NQ; q++) o0 += zq[q] * wrow[q];
        out[(size_t)s * NQ + lane] = o0;
    }
}

extern "C" void kernel_launch(void* const* d_in, const int* in_sizes, int n_in,
                              void* d_out, int out_size, void* d_ws, size_t ws_size,
                              hipStream_t stream) {
    const float* x  = (const float*)d_in[0];
    const float* Wp = (const float*)d_in[1];
    const float* bp = (const float*)d_in[2];
    const float* qw = (const float*)d_in[3];
    const float* Wo = (const float*)d_in[4];
    const float* bo = (const float*)d_in[5];
    float* out = (float*)d_out;

    const int B = in_sizes[0] / D_IN;                  // 8192 states, one per wave
    const int spb = BLOCK / 64;                        // states per block (4)
    const int blocks = (B + spb - 1) / spb;
    hipLaunchKernelGGL(qnet_kernel, dim3(blocks), dim3(BLOCK), 0, stream,
                       x, Wp, bp, qw, Wo, bo, out, B);
}